// Round 6
// baseline (438.542 us; speedup 1.0000x reference)
//
#include <hip/hip_runtime.h>
#include <hip/hip_bf16.h>
#include <stdint.h>

typedef __attribute__((ext_vector_type(8))) short bf16x8;
typedef __attribute__((ext_vector_type(4))) float f32x4;

union FragU { uint4 u; bf16x8 v; };

#define Bn 16
#define Kn 16
#define Sn 512
#define En 512
#define Ln 16
#define Hn 8
#define Dn 64
#define BKTOT 256
#define MTOT (BKTOT*Sn)

__device__ __forceinline__ uint32_t pack_bf16(float lo, float hi) {
  uint32_t a = __float_as_uint(lo) + 0x8000u;
  uint32_t b = __float_as_uint(hi) + 0x8000u;
  return __builtin_amdgcn_perm(b, a, 0x07060302u);  // [b.hi16 : a.hi16]
}
__device__ __forceinline__ uint16_t bf16_1(float x) {
  __hip_bfloat16 h = __float2bfloat16(x);
  return *(uint16_t*)&h;
}
__device__ __forceinline__ void gload_lds16(const void* g, void* l) {
  __builtin_amdgcn_global_load_lds(
      (const __attribute__((address_space(1))) uint32_t*)g,
      (__attribute__((address_space(3))) uint32_t*)l, 16, 0, 0);
}

// ---------------- Kernel 0: prep = xq GEMV + weight conversion ----------------
__global__ __launch_bounds__(256)
void prep_kernel(const float* __restrict__ latent, const float* __restrict__ Wq,
                 const float* __restrict__ Wk, const float* __restrict__ Wv,
                 const float* __restrict__ Wo,
                 float* __restrict__ xq, uint4* __restrict__ Wsw, uint4* __restrict__ Wob)
{
  const int t = threadIdx.x;
  const int b = blockIdx.x;
  if (b < 512) {
    const int j = b;
    const float w0 = Wq[j*En + t];
    const float w1 = Wq[j*En + t + 256];
    float part[Ln];
#pragma unroll
    for (int l = 0; l < Ln; ++l)
      part[l] = w0 * latent[l*En + t] + w1 * latent[l*En + t + 256];
#pragma unroll
    for (int l = 0; l < Ln; ++l) {
      float v = part[l];
#pragma unroll
      for (int off = 32; off > 0; off >>= 1) v += __shfl_down(v, off, 64);
      part[l] = v;
    }
    __shared__ float red[4][Ln];
    const int lane = t & 63, wv = t >> 6;
    if (lane == 0) {
#pragma unroll
      for (int l = 0; l < Ln; ++l) red[wv][l] = part[l];
    }
    __syncthreads();
    if (t < Ln)
      xq[t*En + j] = red[0][t] + red[1][t] + red[2][t] + red[3][t];
  } else if (b < 576) {
    const int idx = (b-512)*256 + t;
    const int kb = idx >> 11;
    const int rem = idx & 2047;
    const int n = rem >> 3, p = rem & 7;
    const int c = p ^ (n & 7);
    const float* src = (n < 128 ? Wk + (size_t)n*En : Wv + (size_t)(n-128)*En) + kb*64 + c*8;
    float4 v0 = *(const float4*)src;
    float4 v1 = *(const float4*)(src+4);
    uint4 o;
    o.x = pack_bf16(v0.x,v0.y); o.y = pack_bf16(v0.z,v0.w);
    o.z = pack_bf16(v1.x,v1.y); o.w = pack_bf16(v1.z,v1.w);
    Wsw[idx] = o;
  } else {
    const int idx = (b-576)*256 + t;
    const float* src = Wo + (size_t)idx*8;
    float4 v0 = *(const float4*)src;
    float4 v1 = *(const float4*)(src+4);
    uint4 o;
    o.x = pack_bf16(v0.x,v0.y); o.y = pack_bf16(v0.z,v0.w);
    o.z = pack_bf16(v1.x,v1.y); o.w = pack_bf16(v1.z,v1.w);
    Wob[idx] = o;
  }
}

// ---------------- Kernel 1: KV projection, 64m x 256n, BK=64, ragged skip ----------------
__global__ __launch_bounds__(256, 4)
void kvproj_kernel(const float* __restrict__ spike, const int* __restrict__ offsets,
                   const float* __restrict__ cosT, const float* __restrict__ sinT,
                   const uint4* __restrict__ Wsw, const int* __restrict__ lengths,
                   uint16_t* __restrict__ Kbuf, uint16_t* __restrict__ Vt)
{
  __shared__ __align__(16) uint16_t Bs[256*64];   // 32 KB, XOR-swizzled rows
  __shared__ __align__(16) uint16_t As[64*64];    // 8 KB, XOR-swizzled rows
  const int t = threadIdx.x;
  const int bk   = blockIdx.x >> 3;
  const int tile = blockIdx.x & 7;
  if (tile * 64 >= lengths[bk]) return;   // rows s>=len never read downstream
  const int m0 = blockIdx.x * 64;
  const int lane = t & 63, wv = t >> 6;
  const int quad = lane >> 4, lr = lane & 15;

  f32x4 acc[4][4];
#pragma unroll
  for (int i=0;i<4;i++)
#pragma unroll
    for (int j=0;j<4;j++) acc[i][j] = (f32x4){0.f,0.f,0.f,0.f};

  const int arow = t >> 3;
  const int aseg = t & 7;

  for (int kb = 0; kb < 8; ++kb) {
    const char* gb = (const char*)(Wsw + kb*2048) + (wv*64 + lane)*16;
    char* lb = (char*)Bs + wv*1024;
#pragma unroll
    for (int i = 0; i < 8; ++i)
      gload_lds16(gb + i*4096, lb + i*4096);
#pragma unroll
    for (int j = 0; j < 2; ++j) {
      const int row = arow + 32*j;
      const float* src = &spike[(size_t)(m0+row)*En + kb*64 + aseg*8];
      float4 v0 = *(const float4*)src;
      float4 v1 = *(const float4*)(src+4);
      uint4 o;
      o.x = pack_bf16(v0.x,v0.y); o.y = pack_bf16(v0.z,v0.w);
      o.z = pack_bf16(v1.x,v1.y); o.w = pack_bf16(v1.z,v1.w);
      *(uint4*)&As[row*64 + (aseg ^ (row & 7))*8] = o;
    }
    __syncthreads();
#pragma unroll
    for (int kk = 0; kk < 2; ++kk) {
      const int c = kk*4 + quad;
      FragU aF[4], bF[4];
#pragma unroll
      for (int mi=0;mi<4;mi++) aF[mi].u = *(const uint4*)&As[(mi*16+lr)*64 + (c ^ (lr & 7))*8];
#pragma unroll
      for (int ni=0;ni<4;ni++) {
        const int n = wv*64 + ni*16 + lr;
        bF[ni].u = *(const uint4*)&Bs[n*64 + (c ^ (n&7))*8];
      }
#pragma unroll
      for (int mi=0;mi<4;mi++)
#pragma unroll
        for (int ni=0;ni<4;ni++)
          acc[mi][ni] = __builtin_amdgcn_mfma_f32_16x16x32_bf16(aF[mi].v, bF[ni].v, acc[mi][ni], 0,0,0);
    }
    __syncthreads();
  }

  const int sbase = m0 & 511;
  if (wv < 2) {
#pragma unroll
    for (int mi=0;mi<4;mi++) {
#pragma unroll
      for (int r=0;r<4;r++) {
        const int s = sbase + mi*16 + quad*4 + r;
        const int off = offsets[m0 + mi*16 + quad*4 + r];
#pragma unroll
        for (int ni=0;ni<4;ni++) {
          const int d = ni*16 + lr;
          const float v = acc[mi][ni][r];
          const float p = acc[mi][ni^2][r];
          const float rot = (ni < 2) ? -p : p;
          const float cc  = cosT[off*Dn + d];
          const float sn  = sinT[off*Dn + d];
          Kbuf[((size_t)(bk*512 + s))*128 + wv*64 + d] = bf16_1(v*cc + rot*sn);
        }
      }
    }
  } else {
    const int nbase = (wv - 2) * 64;
#pragma unroll
    for (int mi=0;mi<4;mi++) {
#pragma unroll
      for (int ni=0;ni<4;ni++) {
        const int np = nbase + ni*16 + lr;
        const int s  = sbase + mi*16 + quad*4;
        uint2 pk;
        pk.x = pack_bf16(acc[mi][ni][0], acc[mi][ni][1]);
        pk.y = pack_bf16(acc[mi][ni][2], acc[mi][ni][3]);
        *(uint2*)&Vt[((size_t)(bk*128 + np))*512 + s] = pk;
      }
    }
  }
}

// ---------------- Kernel 2: flash attention partials, block = (bk, kvh, half) ----------------
// Partial slot pbase holds 64 LOCAL rows: hlL = (h&3)*16 + l. Opart stride 4096 f32,
// MLpart stride 128 f32 (64 (m,l) pairs).
__global__ __launch_bounds__(256)
void attn_kernel(const float* __restrict__ xq, const uint16_t* __restrict__ Kbuf,
                 const uint16_t* __restrict__ Vt, const int* __restrict__ lengths,
                 float* __restrict__ Opart, float* __restrict__ MLpart)
{
  __shared__ __align__(16) uint16_t Ks [128*72];
  __shared__ __align__(16) uint16_t Vts[64*136];
  __shared__ __align__(16) uint16_t Ps [4*16*136];

  const int t = threadIdx.x;
  const int bk   = blockIdx.x >> 2;
  const int kvh  = (blockIdx.x >> 1) & 1;
  const int half = blockIdx.x & 1;
  const int len = lengths[bk];
  const size_t pbase = ((size_t)bk*2 + kvh)*2 + half;

  if (half*256 >= len) {              // empty half: sentinel (m=-inf, l=0) for all 64 local rows
    if (t < 128) MLpart[pbase*128 + t] = (t & 1) ? 0.f : -3.0e38f;
    return;
  }

  const int w = t >> 6, lane = t & 63;
  const int quad = lane >> 4, lr = lane & 15;
  const int h = kvh*4 + w;

  FragU aQ[2];
#pragma unroll
  for (int kk=0;kk<2;kk++) {
    const float* qp = &xq[lr*En + h*Dn + kk*32 + quad*8];
    float4 q0 = *(const float4*)qp;
    float4 q1 = *(const float4*)(qp + 4);
    aQ[kk].u.x = pack_bf16(q0.x*0.125f, q0.y*0.125f);
    aQ[kk].u.y = pack_bf16(q0.z*0.125f, q0.w*0.125f);
    aQ[kk].u.z = pack_bf16(q1.x*0.125f, q1.y*0.125f);
    aQ[kk].u.w = pack_bf16(q1.z*0.125f, q1.w*0.125f);
  }

  float m_run[4], l_run[4], alpha[4];
  f32x4 oacc[4];
#pragma unroll
  for (int r=0;r<4;r++){ m_run[r] = -3.0e38f; l_run[r] = 0.f; }
#pragma unroll
  for (int nd=0;nd<4;nd++) oacc[nd] = (f32x4){0.f,0.f,0.f,0.f};

  const int krow = t >> 1, kseg = t & 1;
  const int vrow = t >> 2, vseg = t & 3;

  for (int ci = 0; ci < 2; ++ci) {
    const int s0 = (half*2 + ci) * 128;
    if (s0 >= len) break;
    __syncthreads();
    {
      const uint16_t* g = &Kbuf[((size_t)(bk*512 + s0 + krow))*128 + kvh*64 + kseg*32];
      uint16_t* dst = &Ks[krow*72 + kseg*32];
      uint4 a0 = *(const uint4*)g, a1 = *(const uint4*)(g+8);
      uint4 a2 = *(const uint4*)(g+16), a3 = *(const uint4*)(g+24);
      *(uint4*)dst = a0; *(uint4*)(dst+8) = a1; *(uint4*)(dst+16) = a2; *(uint4*)(dst+24) = a3;

      const uint16_t* gv = &Vt[((size_t)(bk*128 + kvh*64 + vrow))*512 + s0 + vseg*32];
      uint16_t* dv = &Vts[vrow*136 + vseg*32];
      uint4 b0 = *(const uint4*)gv, b1 = *(const uint4*)(gv+8);
      uint4 b2 = *(const uint4*)(gv+16), b3 = *(const uint4*)(gv+24);
      *(uint4*)dv = b0; *(uint4*)(dv+8) = b1; *(uint4*)(dv+16) = b2; *(uint4*)(dv+24) = b3;
    }
    __syncthreads();

    f32x4 sc[8];
#pragma unroll
    for (int ni=0;ni<8;ni++) {
      FragU b0, b1;
      b0.u = *(const uint4*)&Ks[(ni*16+lr)*72 + quad*8];
      b1.u = *(const uint4*)&Ks[(ni*16+lr)*72 + 32 + quad*8];
      f32x4 a = (f32x4){0.f,0.f,0.f,0.f};
      a = __builtin_amdgcn_mfma_f32_16x16x32_bf16(aQ[0].v, b0.v, a, 0,0,0);
      a = __builtin_amdgcn_mfma_f32_16x16x32_bf16(aQ[1].v, b1.v, a, 0,0,0);
      sc[ni] = a;
    }
#pragma unroll
    for (int ni=0;ni<8;ni++)
      if (s0 + ni*16 + lr >= len)
        sc[ni] = (f32x4){-3.0e38f,-3.0e38f,-3.0e38f,-3.0e38f};

#pragma unroll
    for (int r=0;r<4;r++) {
      float mx = sc[0][r];
#pragma unroll
      for (int ni=1;ni<8;ni++) mx = fmaxf(mx, sc[ni][r]);
#pragma unroll
      for (int o=1;o<16;o<<=1) mx = fmaxf(mx, __shfl_xor(mx, o, 16));
      const float mnew = fmaxf(m_run[r], mx);
      alpha[r] = __expf(m_run[r] - mnew);
      m_run[r] = mnew;
      float ssum = 0.f;
#pragma unroll
      for (int ni=0;ni<8;ni++) {
        float p = __expf(sc[ni][r] - mnew);
        sc[ni][r] = p;
        ssum += p;
      }
#pragma unroll
      for (int o=1;o<16;o<<=1) ssum += __shfl_xor(ssum, o, 16);
      l_run[r] = l_run[r]*alpha[r] + ssum;
    }

#pragma unroll
    for (int ni=0;ni<8;ni++)
#pragma unroll
      for (int r=0;r<4;r++)
        Ps[(w*16 + quad*4 + r)*136 + ni*16 + lr] = bf16_1(sc[ni][r]);

#pragma unroll
    for (int nd=0;nd<4;nd++)
#pragma unroll
      for (int r=0;r<4;r++) oacc[nd][r] *= alpha[r];

#pragma unroll
    for (int kk=0;kk<4;kk++) {
      FragU aP;
      aP.u = *(const uint4*)&Ps[(w*16 + lr)*136 + kk*32 + quad*8];
#pragma unroll
      for (int nd=0;nd<4;nd++) {
        FragU bV;
        bV.u = *(const uint4*)&Vts[(nd*16+lr)*136 + kk*32 + quad*8];
        oacc[nd] = __builtin_amdgcn_mfma_f32_16x16x32_bf16(aP.v, bV.v, oacc[nd], 0,0,0);
      }
    }
  }

  // write unnormalized partials (LOCAL row index)
#pragma unroll
  for (int r=0;r<4;r++) {
    const int l = quad*4 + r;
    const int hlL = w*16 + l;                 // local: (h&3)*16 + l
#pragma unroll
    for (int nd=0;nd<4;nd++)
      Opart[pbase*4096 + hlL*64 + nd*16 + lr] = oacc[nd][r];
    if (lr == 0) {
      MLpart[pbase*128 + hlL*2]     = m_run[r];
      MLpart[pbase*128 + hlL*2 + 1] = l_run[r];
    }
  }
}

// ---------------- Kernel 2b: merge two halves -> attn_out (bf16) ----------------
__global__ __launch_bounds__(256)
void attn_merge_kernel(const float* __restrict__ Opart, const float* __restrict__ MLpart,
                       uint16_t* __restrict__ attn_out)
{
  const int bk = blockIdx.x;
  const int t = threadIdx.x;
  const int hlG = t >> 1;         // global h*16 + l, 0..127
  const int dh = t & 1;           // 32-d half
  const int h = hlG >> 4;
  const int l = hlG & 15;
  const int kvh = h >> 2;
  const int hlL = (h & 3)*16 + l; // local row within partial slot
  const size_t pb = ((size_t)bk*2 + kvh)*2;

  const float m1 = MLpart[pb*128 + hlL*2],       l1 = MLpart[pb*128 + hlL*2 + 1];
  const float m2 = MLpart[(pb+1)*128 + hlL*2],   l2 = MLpart[(pb+1)*128 + hlL*2 + 1];
  const float m  = fmaxf(m1, m2);
  const float a1 = __expf(m1 - m), a2 = __expf(m2 - m);
  const float inv = 1.0f / (a1*l1 + a2*l2);
  const float w1 = a1*inv, w2 = a2*inv;

  const float* O1 = &Opart[pb*4096 + hlL*64 + dh*32];
  const float* O2 = &Opart[(pb+1)*4096 + hlL*64 + dh*32];
  uint16_t* dst = &attn_out[((size_t)bk*16 + l)*512 + h*64 + dh*32];
#pragma unroll
  for (int i = 0; i < 8; ++i) {
    float4 o1 = *(const float4*)(O1 + i*4);
    float4 o2 = *(const float4*)(O2 + i*4);
    uint2 pk;
    pk.x = pack_bf16(w1*o1.x + w2*o2.x, w1*o1.y + w2*o2.y);
    pk.y = pack_bf16(w1*o1.z + w2*o2.z, w1*o1.w + w2*o2.w);
    *(uint2*)(dst + i*4) = pk;
  }
}

// ---------------- Kernel 3: out = attn_out(4096x512,bf16) @ Wob^T (bf16 MFMA) ----------------
__global__ __launch_bounds__(256)
void oproj_kernel(const uint16_t* __restrict__ Ab, const uint16_t* __restrict__ Wob,
                  float* __restrict__ out)
{
  __shared__ __align__(16) uint16_t As[128*72];
  __shared__ __align__(16) uint16_t Bs[128*72];
  const int t = threadIdx.x;
  const int m0 = (blockIdx.x >> 2) * 128;
  const int n0 = (blockIdx.x & 3) * 128;
  const int lane = t & 63, wv = t >> 6;
  const int quad = lane >> 4, lr = lane & 15;
  const int wm = wv >> 1, wn = wv & 1;

  f32x4 acc[4][4];
#pragma unroll
  for (int i=0;i<4;i++)
#pragma unroll
    for (int j=0;j<4;j++) acc[i][j] = (f32x4){0.f,0.f,0.f,0.f};

  const int srow = t >> 3, sseg = t & 7;
  for (int kb = 0; kb < 8; ++kb) {
#pragma unroll
    for (int j = 0; j < 4; ++j) {
      const int row = srow + 32*j;
      *(uint4*)&As[row*72 + sseg*8] = *(const uint4*)&Ab [(size_t)(m0+row)*512 + kb*64 + sseg*8];
      *(uint4*)&Bs[row*72 + sseg*8] = *(const uint4*)&Wob[(size_t)(n0+row)*512 + kb*64 + sseg*8];
    }
    __syncthreads();
#pragma unroll
    for (int kk = 0; kk < 2; ++kk) {
      const int c = kk*4 + quad;
      FragU aF[4], bF[4];
#pragma unroll
      for (int mi=0;mi<4;mi++) aF[mi].u = *(const uint4*)&As[(wm*64+mi*16+lr)*72 + c*8];
#pragma unroll
      for (int ni=0;ni<4;ni++) bF[ni].u = *(const uint4*)&Bs[(wn*64+ni*16+lr)*72 + c*8];
#pragma unroll
      for (int mi=0;mi<4;mi++)
#pragma unroll
        for (int ni=0;ni<4;ni++)
          acc[mi][ni] = __builtin_amdgcn_mfma_f32_16x16x32_bf16(aF[mi].v, bF[ni].v, acc[mi][ni], 0,0,0);
    }
    __syncthreads();
  }
#pragma unroll
  for (int mi=0;mi<4;mi++)
#pragma unroll
    for (int r=0;r<4;r++)
#pragma unroll
      for (int ni=0;ni<4;ni++)
        out[(size_t)(m0 + wm*64 + mi*16 + quad*4 + r)*512 + n0 + wn*64 + ni*16 + lr] = acc[mi][ni][r];
}

// ---------------- launch ----------------
extern "C" void kernel_launch(void* const* d_in, const int* in_sizes, int n_in,
                              void* d_out, int out_size, void* d_ws, size_t ws_size,
                              hipStream_t stream)
{
  const float* spike   = (const float*)d_in[0];
  const int*   offsets = (const int*)d_in[1];
  const int*   lengths = (const int*)d_in[2];
  const float* cosT    = (const float*)d_in[3];
  const float* sinT    = (const float*)d_in[4];
  const float* latent  = (const float*)d_in[5];
  const float* Wq      = (const float*)d_in[6];
  const float* Wk      = (const float*)d_in[7];
  const float* Wv      = (const float*)d_in[8];
  const float* Wo      = (const float*)d_in[9];
  float* out = (float*)d_out;

  char* ws = (char*)d_ws;
  float*    xq   = (float*)ws;                                   // 32 KB (reserve 64 KB)
  uint4*    Wsw  = (uint4*)(ws + 65536);                         // 256 KB
  uint4*    Wob  = (uint4*)(ws + 65536 + 262144);                // 512 KB
  uint16_t* Kbuf = (uint16_t*)(ws + 1048576);                    // 32 MB
  uint16_t* Vt   = (uint16_t*)(ws + 34603008ull);                // 32 MB
  uint16_t* attn_out = (uint16_t*)(ws + 68157440ull);            // 4 MB
  float*    Opart  = (float*)(ws + 72351744ull);                 // 16 MB
  float*    MLpart = (float*)(ws + 89128960ull);                 // 0.5 MB

  hipLaunchKernelGGL(prep_kernel,   dim3(704),  dim3(256), 0, stream,
                     latent, Wq, Wk, Wv, Wo, xq, Wsw, Wob);
  hipLaunchKernelGGL(kvproj_kernel, dim3(2048), dim3(256), 0, stream,
                     spike, offsets, cosT, sinT, Wsw, lengths, Kbuf, Vt);
  hipLaunchKernelGGL(attn_kernel,   dim3(1024), dim3(256), 0, stream,
                     xq, Kbuf, Vt, lengths, Opart, MLpart);
  hipLaunchKernelGGL(attn_merge_kernel, dim3(256), dim3(256), 0, stream,
                     Opart, MLpart, attn_out);
  hipLaunchKernelGGL(oproj_kernel,  dim3(128),  dim3(256), 0, stream,
                     attn_out, (const uint16_t*)Wob, out);
}